// Round 14
// baseline (208.414 us; speedup 1.0000x reference)
//
#include <hip/hip_runtime.h>
#include <hip/hip_bf16.h>

typedef __bf16 bf16_t;
typedef __bf16 bf16x8 __attribute__((ext_vector_type(8)));
typedef float f32x4 __attribute__((ext_vector_type(4)));
typedef __fp16 f16x2 __attribute__((ext_vector_type(2)));

#define BATCH 4
#define SEQ 4096
#define FIN 33
#define DIM 64
#define LOG2E 1.4426950408889634f

__device__ __forceinline__ float dexp2(float x) { return __builtin_amdgcn_exp2f(x); }
__device__ __forceinline__ unsigned pk(float a, float b)
{ return __builtin_bit_cast(unsigned, __builtin_amdgcn_cvt_pkrtz(a, b)); }
__device__ __forceinline__ f16x2 uph(unsigned u)
{ return __builtin_bit_cast(f16x2, u); }
__device__ __forceinline__ float f16lo(unsigned u)
{ return (float)uph(u)[0]; }

__device__ __forceinline__ f32x4 mm2(bf16x8 a0, bf16x8 a1, bf16x8 b0, bf16x8 b1)
{
    f32x4 acc = {0.f, 0.f, 0.f, 0.f};
    acc = __builtin_amdgcn_mfma_f32_16x16x32_bf16(a0, b0, acc, 0, 0, 0);
    acc = __builtin_amdgcn_mfma_f32_16x16x32_bf16(a1, b1, acc, 0, 0, 0);
    return acc;
}

// ---------------- Kernel 1: q/k affine projections ----------------
__global__ __launch_bounds__(256) void qk_proj_kernel(
    const float* __restrict__ x, const float* __restrict__ Wq,
    const float* __restrict__ bq, const float* __restrict__ Wk,
    const float* __restrict__ bk,
    bf16_t* __restrict__ qout, bf16_t* __restrict__ kout)
{
    __shared__ float sWq[FIN * DIM];
    __shared__ float sWk[FIN * DIM];
    __shared__ float sb[2 * DIM];
    const int t = threadIdx.x;
    for (int i = t; i < FIN * DIM; i += 256) { sWq[i] = Wq[i]; sWk[i] = Wk[i]; }
    if (t < DIM) { sb[t] = bq[t]; sb[DIM + t] = bk[t]; }
    __syncthreads();

    const int row = blockIdx.x * 4 + (t >> 6);
    const int d   = t & 63;
    const float* xr = x + (size_t)row * FIN;
    float qacc = sb[d], kacc = sb[DIM + d];
#pragma unroll
    for (int f = 0; f < FIN; ++f) {
        const float xv = xr[f];
        qacc += xv * sWq[f * DIM + d];
        kacc += xv * sWk[f * DIM + d];
    }
    qout[(size_t)row * DIM + d] = (bf16_t)qacc;
    kout[(size_t)row * DIM + d] = (bf16_t)kacc;
}

#define LDK(ct, h) (*reinterpret_cast<const bf16x8*>(kw + (size_t)(ct) * 16 * DIM + (h) * 32))

// ---------------- Kernel 2: M and Z ----------------
// 1024 WGs x 256 thr (4 waves). WG = one 16-row block; wave w = cols [w*1024,+1024).
// Two sweeps (max, then Z). Designed <= 64 VGPR: single row-block, depth-2 pipeline.
__global__ __launch_bounds__(256) void mz_kernel(
    const bf16_t* __restrict__ qg, const bf16_t* __restrict__ kg,
    float* __restrict__ cMg, float* __restrict__ invZg)
{
    const int wg   = ((blockIdx.x & 7) << 7) | (blockIdx.x >> 3);  // XCD swizzle (1024 = 8*128)
    const int b    = wg >> 8;
    const int t    = threadIdx.x;
    const int w    = t >> 6;            // wave 0..3
    const int l    = t & 63;
    const int lr   = l & 15;
    const int kg4  = l >> 4;
    const int col0 = w << 10;

    const bf16_t* kw = kg + ((size_t)b * SEQ + col0 + lr) * DIM + kg4 * 8;
    const bf16_t* qb = qg + (size_t)(wg * 16) * DIM;

    const bf16x8 a0 = *reinterpret_cast<const bf16x8*>(qb + lr * DIM + kg4 * 8);
    const bf16x8 a1 = *reinterpret_cast<const bf16x8*>(qb + lr * DIM + 32 + kg4 * 8);

    __shared__ float redM[4][16];
    __shared__ float redZ[4][16];

    // ---- sweep 1: row max ----
    float vmax[4] = {-3.4e38f, -3.4e38f, -3.4e38f, -3.4e38f};
    {
        bf16x8 p0a = LDK(0, 0), p0b = LDK(0, 1);
        bf16x8 p1a = LDK(1, 0), p1b = LDK(1, 1);
#pragma unroll 4
        for (int ct = 0; ct < 64; ct += 2) {
            f32x4 acc0 = mm2(a0, a1, p0a, p0b);
            if (ct + 2 < 64) { p0a = LDK(ct + 2, 0); p0b = LDK(ct + 2, 1); }
#pragma unroll
            for (int j = 0; j < 4; ++j) vmax[j] = fmaxf(vmax[j], acc0[j]);
            f32x4 acc1 = mm2(a0, a1, p1a, p1b);
            if (ct + 3 < 64) { p1a = LDK(ct + 3, 0); p1b = LDK(ct + 3, 1); }
#pragma unroll
            for (int j = 0; j < 4; ++j) vmax[j] = fmaxf(vmax[j], acc1[j]);
        }
    }
#pragma unroll
    for (int m = 1; m < 16; m <<= 1) {
#pragma unroll
        for (int j = 0; j < 4; ++j) vmax[j] = fmaxf(vmax[j], __shfl_xor(vmax[j], m, 64));
    }
    if (lr == 0) {
#pragma unroll
        for (int j = 0; j < 4; ++j) redM[w][kg4 * 4 + j] = vmax[j];
    }
    __syncthreads();
    float cM[4];
#pragma unroll
    for (int j = 0; j < 4; ++j) {
        const int r = kg4 * 4 + j;
        const float mm = fmaxf(fmaxf(redM[0][r], redM[1][r]), fmaxf(redM[2][r], redM[3][r]));
        cM[j] = LOG2E / mm;
    }

    // ---- sweep 2: Z ----
    float vsum[4] = {0.f, 0.f, 0.f, 0.f};
    {
        bf16x8 p0a = LDK(0, 0), p0b = LDK(0, 1);
        bf16x8 p1a = LDK(1, 0), p1b = LDK(1, 1);
#pragma unroll 4
        for (int ct = 0; ct < 64; ct += 2) {
            f32x4 acc0 = mm2(a0, a1, p0a, p0b);
            if (ct + 2 < 64) { p0a = LDK(ct + 2, 0); p0b = LDK(ct + 2, 1); }
#pragma unroll
            for (int j = 0; j < 4; ++j) vsum[j] += dexp2(fmaf(acc0[j], cM[j], -LOG2E));
            f32x4 acc1 = mm2(a0, a1, p1a, p1b);
            if (ct + 3 < 64) { p1a = LDK(ct + 3, 0); p1b = LDK(ct + 3, 1); }
#pragma unroll
            for (int j = 0; j < 4; ++j) vsum[j] += dexp2(fmaf(acc1[j], cM[j], -LOG2E));
        }
    }
#pragma unroll
    for (int m = 1; m < 16; m <<= 1) {
#pragma unroll
        for (int j = 0; j < 4; ++j) vsum[j] += __shfl_xor(vsum[j], m, 64);
    }
    if (lr == 0) {
#pragma unroll
        for (int j = 0; j < 4; ++j) redZ[w][kg4 * 4 + j] = vsum[j];
    }
    __syncthreads();
    if (t < 16) {
        const float mm = fmaxf(fmaxf(redM[0][t], redM[1][t]), fmaxf(redM[2][t], redM[3][t]));
        const float zz = redZ[0][t] + redZ[1][t] + redZ[2][t] + redZ[3][t];
        cMg[wg * 16 + t]   = LOG2E / mm;
        invZg[wg * 16 + t] = 1.0f / zz;
    }
}

// ---------------- Kernel 3: recompute + exp -> LDS -> CONTIGUOUS stores ----------------
// 2048 WGs x 512 thr (8 waves). WG = 16 rows x 2048 cols (half a row-band).
// Wave w computes cols [w*256,+256) into its LDS slice; after one barrier each
// wave stores TWO COMPLETE ROWS (2w, 2w+1): every store instruction is 1 KB
// contiguous (64 lanes x dwordx4), each row an 8 KB contiguous run.
__global__ __launch_bounds__(512) void p_kernel(
    const bf16_t* __restrict__ qg, const bf16_t* __restrict__ kg,
    const float* __restrict__ cMg, const float* __restrict__ invZg,
    float* __restrict__ out)
{
    const int wgid = ((blockIdx.x & 7) << 8) | (blockIdx.x >> 3);  // XCD swizzle (2048 = 8*256)
    const int rb   = wgid >> 1;          // row-block 0..1023
    const int half = wgid & 1;           // col half 0..1
    const int b    = rb >> 8;
    const int t    = threadIdx.x;
    const int w    = t >> 6;             // wave 0..7
    const int l    = t & 63;
    const int lr   = l & 15;
    const int kg4  = l >> 4;
    const int col0 = half * 2048 + w * 256;

    __shared__ uint2 sS[8][4][256];      // [wave][row-group][col]: packed e (fp16 x4 rows)

    // per-lane row constants for the compute mapping
    float cM[4];
#pragma unroll
    for (int j = 0; j < 4; ++j) cM[j] = cMg[rb * 16 + kg4 * 4 + j];

    const bf16_t* qb = qg + (size_t)(rb * 16) * DIM;
    const bf16x8 a0 = *reinterpret_cast<const bf16x8*>(qb + lr * DIM + kg4 * 8);
    const bf16x8 a1 = *reinterpret_cast<const bf16x8*>(qb + lr * DIM + 32 + kg4 * 8);
    const bf16_t* kw = kg + ((size_t)b * SEQ + col0 + lr) * DIM + kg4 * 8;

    uint2* const sp = &sS[w][kg4][lr];

    // ---- sweep: k loads + MFMA + exp + pack -> LDS ----
    {
        bf16x8 p0a = LDK(0, 0), p0b = LDK(0, 1);
        bf16x8 p1a = LDK(1, 0), p1b = LDK(1, 1);
#pragma unroll
        for (int ct = 0; ct < 16; ct += 2) {
            f32x4 acc0 = mm2(a0, a1, p0a, p0b);
            if (ct + 2 < 16) { p0a = LDK(ct + 2, 0); p0b = LDK(ct + 2, 1); }
            {
                const float e0 = dexp2(fmaf(acc0[0], cM[0], -LOG2E));
                const float e1 = dexp2(fmaf(acc0[1], cM[1], -LOG2E));
                const float e2 = dexp2(fmaf(acc0[2], cM[2], -LOG2E));
                const float e3 = dexp2(fmaf(acc0[3], cM[3], -LOG2E));
                sp[ct * 16] = make_uint2(pk(e0, e1), pk(e2, e3));
            }
            f32x4 acc1 = mm2(a0, a1, p1a, p1b);
            if (ct + 3 < 16) { p1a = LDK(ct + 3, 0); p1b = LDK(ct + 3, 1); }
            {
                const float e0 = dexp2(fmaf(acc1[0], cM[0], -LOG2E));
                const float e1 = dexp2(fmaf(acc1[1], cM[1], -LOG2E));
                const float e2 = dexp2(fmaf(acc1[2], cM[2], -LOG2E));
                const float e3 = dexp2(fmaf(acc1[3], cM[3], -LOG2E));
                sp[(ct + 1) * 16] = make_uint2(pk(e0, e1), pk(e2, e3));
            }
        }
    }
    __syncthreads();

    // ---- store pass: wave w stores rows 2w and 2w+1, fully contiguous ----
    {
        const int rA = 2 * w;                 // local rows
        const int g  = w >> 1;                // row-group in each slice
        const bool useY = (w & 1);            // rows 4g+2,4g+3 live in .y
        const float izA = invZg[rb * 16 + rA];
        const float izB = invZg[rb * 16 + rA + 1];
        float* obA = out + ((size_t)(rb * 16 + rA)) * SEQ + half * 2048;
        float* obB = obA + SEQ;
#pragma unroll
        for (int it = 0; it < 8; ++it) {
            // slice `it`, columns 4l..4l+3 -> elems sS[it][g][4l..4l+3] (32 B contiguous)
            const uint4 U0 = *reinterpret_cast<const uint4*>(&sS[it][g][4 * l]);
            const uint4 U1 = *reinterpret_cast<const uint4*>(&sS[it][g][4 * l + 2]);
            const unsigned w0 = useY ? U0.y : U0.x;
            const unsigned w1 = useY ? U0.w : U0.z;
            const unsigned w2 = useY ? U1.y : U1.x;
            const unsigned w3 = useY ? U1.w : U1.z;
            f32x4 vA, vB;
            vA[0] = f16lo(w0); vA[1] = f16lo(w1); vA[2] = f16lo(w2); vA[3] = f16lo(w3);
            vB[0] = f16lo(w0 >> 16); vB[1] = f16lo(w1 >> 16);
            vB[2] = f16lo(w2 >> 16); vB[3] = f16lo(w3 >> 16);
            *reinterpret_cast<f32x4*>(obA + it * 256 + 4 * l) = vA * izA;
            *reinterpret_cast<f32x4*>(obB + it * 256 + 4 * l) = vB * izB;
        }
    }
}

extern "C" void kernel_launch(void* const* d_in, const int* in_sizes, int n_in,
                              void* d_out, int out_size, void* d_ws, size_t ws_size,
                              hipStream_t stream)
{
    const float* x  = (const float*)d_in[0];
    const float* Wq = (const float*)d_in[1];
    const float* bq = (const float*)d_in[2];
    const float* Wk = (const float*)d_in[3];
    const float* bk = (const float*)d_in[4];
    float* out = (float*)d_out;

    bf16_t* qws = (bf16_t*)d_ws;
    bf16_t* kws = qws + (size_t)BATCH * SEQ * DIM;
    float*  cMg = (float*)(kws + (size_t)BATCH * SEQ * DIM);
    float*  iZg = cMg + (size_t)BATCH * SEQ;

    qk_proj_kernel<<<(BATCH * SEQ) / 4, 256, 0, stream>>>(x, Wq, bq, Wk, bk, qws, kws);
    mz_kernel<<<BATCH * (SEQ / 16), 256, 0, stream>>>(qws, kws, cMg, iZg);
    p_kernel<<<BATCH * (SEQ / 16) * 2, 512, 0, stream>>>(qws, kws, cMg, iZg, out);
}